// Round 8
// baseline (95.963 us; speedup 1.0000x reference)
//
#include <hip/hip_runtime.h>
#include <cstdint>

#define NV 200000
#define NCOLS 5
#define P 128
#define NE 8192
#define NC 1024

// Kernel 1: gather all clusters' coords once into dense float4 array.
// ws[c*P + p] = (data[v,1], data[v,2], data[v,3], 0) where v = clusts[c,p].
__global__ __launch_bounds__(256) void gather_kernel(
    const float* __restrict__ data,
    const int*   __restrict__ clusts,
    float4*      __restrict__ ws)
{
    const int idx = blockIdx.x * 256 + threadIdx.x;   // 0 .. NC*P-1
    const int v = clusts[idx];
    ws[idx] = make_float4(data[v * NCOLS + 1], data[v * NCOLS + 2],
                          data[v * NCOLS + 3], 0.f);
}

template <bool USE_WS>
__device__ __forceinline__ float4 load_pt(const float* __restrict__ data,
                                          const int*   __restrict__ clusts,
                                          const float4* __restrict__ ws,
                                          int c, int p)
{
    if (USE_WS) return ws[c * P + p];
    const int v = clusts[c * P + p];
    return make_float4(data[v * NCOLS + 1], data[v * NCOLS + 2],
                       data[v * NCOLS + 3], 0.f);
}

// R5's proven compute core, verbatim: 8 independent (value,k) min-chains,
// rolled groups of 8 a-points, exact rn arithmetic, packed (d2,flat) u64
// key combine + 64-lane shfl reduce. Returns the wave-min key (valid in
// all lanes' lane-0-reachable path; only lane 0 uses it).
__device__ __forceinline__ unsigned long long
wave_min_key(const float4* __restrict__ x1p,
             const float* __restrict__ bx, const float* __restrict__ by,
             const float* __restrict__ bz, int ti, int tj)
{
    float bd[8];
    int   bk[8];
    #pragma unroll
    for (int m = 0; m < 8; ++m) { bd[m] = __builtin_inff(); bk[m] = 0; }

    // Exact replication of reference fp32 arithmetic: (dx*dx + dy*dy) + dz*dz,
    // no FMA contraction (argmin tie-breaking must match numpy).
    #pragma unroll 1
    for (int kk = 0; kk < 4; ++kk) {
        float ax[8], ay[8], az[8];
        #pragma unroll
        for (int u = 0; u < 8; ++u) {
            const float4 av = x1p[ti + 4 * (kk * 8 + u)];   // broadcast ds_read
            ax[u] = av.x; ay[u] = av.y; az[u] = av.z;
        }
        #pragma unroll
        for (int u = 0; u < 8; ++u) {
            #pragma unroll
            for (int m = 0; m < 8; ++m) {
                const float dx = __fsub_rn(ax[u], bx[m]);
                const float dy = __fsub_rn(ay[u], by[m]);
                const float dz = __fsub_rn(az[u], bz[m]);
                const float d2 = __fadd_rn(__fadd_rn(__fmul_rn(dx, dx), __fmul_rn(dy, dy)),
                                           __fmul_rn(dz, dz));
                if (d2 < bd[m]) { bd[m] = d2; bk[m] = kk * 8 + u; }  // k ascending
            }
        }
    }

    // Combine the 8 chains exactly via packed (d2, flat) keys.
    const int base = ti * P + tj;
    unsigned long long key = 0xffffffffffffffffull;
    #pragma unroll
    for (int m = 0; m < 8; ++m) {
        const unsigned flat = (unsigned)(base + (m << 4) + (bk[m] << 9)); // +512*k
        const unsigned long long km =
            ((unsigned long long)__float_as_uint(bd[m]) << 32) | flat;
        if (km < key) key = km;
    }

    // Wave-level (64-lane) min reduce.
    for (int off = 32; off > 0; off >>= 1) {
        unsigned long long other = __shfl_down(key, off, 64);
        if (other < key) key = other;
    }
    return key;
}

template <bool USE_WS>
__device__ __forceinline__ void epilogue(
    unsigned long long key, const float4* __restrict__ x1p,
    const float* __restrict__ data, const int* __restrict__ clusts,
    const float4* __restrict__ ws, int c2, int e,
    float* __restrict__ out)
{
    const int flat = (int)(key & 0xffffffffull);
    const int i1 = flat >> 7;
    const int i2 = flat & (P - 1);

    const float4 p1 = x1p[i1];
    const float4 p2 = load_pt<USE_WS>(data, clusts, ws, c2, i2);
    const float v1x = p1.x, v1y = p1.y, v1z = p1.z;
    const float v2x = p2.x, v2y = p2.y, v2z = p2.z;

    const float dx = v1x - v2x, dy = v1y - v2y, dz = v1z - v2z;
    const float lend = sqrtf(dx * dx + dy * dy + dz * dz);

    float nx, ny, nz;
    if (lend > 0.f) { nx = dx / lend; ny = dy / lend; nz = dz / lend; }
    else            { nx = dx;        ny = dy;        nz = dz;        }

    const float B0 = nx * nx, B1 = nx * ny, B2 = nx * nz;
    const float B3 = ny * nx, B4 = ny * ny, B5 = ny * nz;
    const float B6 = nz * nx, B7 = nz * ny, B8 = nz * nz;

    // Row layout (38 floats): [v1 v2 n lend B] [v2 v1 -n lend B].
    // 152-byte rows are 8-aligned -> float2 stores are safe.
    float2* o = reinterpret_cast<float2*>(out + (size_t)e * 38);
    o[0]  = make_float2(v1x, v1y);
    o[1]  = make_float2(v1z, v2x);
    o[2]  = make_float2(v2y, v2z);
    o[3]  = make_float2(nx,  ny);
    o[4]  = make_float2(nz,  lend);
    o[5]  = make_float2(B0,  B1);
    o[6]  = make_float2(B2,  B3);
    o[7]  = make_float2(B4,  B5);
    o[8]  = make_float2(B6,  B7);
    o[9]  = make_float2(B8,  v2x);
    o[10] = make_float2(v2y, v2z);
    o[11] = make_float2(v1x, v1y);
    o[12] = make_float2(v1z, -nx);
    o[13] = make_float2(-ny, -nz);
    o[14] = make_float2(lend, B0);
    o[15] = make_float2(B1,  B2);
    o[16] = make_float2(B3,  B4);
    o[17] = make_float2(B5,  B6);
    o[18] = make_float2(B7,  B8);
}

// Edge kernel: TWO EDGES PER WAVE, software-pipelined staging.
//
// R0-R7 established: within-edge issue structure (occupancy 2-8 waves/SIMD,
// serial vs 8-chain ILP, group size, scalar vs packed fp32) cannot move the
// edge kernel off ~38 us (~53% duty). Untried axis: the per-edge serial
// {stage -> drain -> compute -> reduce -> epilogue} exposes ~1500-2000 cyc
// of staging latency + serial tail per edge, and all waves convoy in phase.
// This version: wave W handles edges W and W+4096.
//  - all edge-0 loads AND edge-1's x1 loads issue up-front;
//  - edge-1's x1 ds_write + b loads issue right after edge-0's compute,
//    flying under edge-0's reduce + epilogue;
//  - b tile loaded straight to registers (coalesced: for fixed m, the 16
//    tj-lanes read 16 consecutive float4 = 256B, 4-way broadcast over ti),
//    eliminating the x2 LDS staging entirely.
// Compute core, chains, tie-break key, reduce: byte-identical to R5
// (HW-proven at 93.2 us total, absmax 0; contract(off) keeps epilogue
// bit-exact vs JAX).
template <bool USE_WS>
__global__ __launch_bounds__(128) void clust_geo_edge_kernel(
    const float*  __restrict__ data,
    const int*    __restrict__ clusts,
    const int*    __restrict__ edge_index,
    const float4* __restrict__ ws,
    float*        __restrict__ out)
{
#pragma clang fp contract(off)
    const int w    = threadIdx.x >> 6;        // wave id within block: 0/1
    const int lane = threadIdx.x & 63;
    const int W    = blockIdx.x * 2 + w;      // global wave id, 0..4095

    __shared__ float4 x1buf[2][2][P];         // [wave][dbuf][point] = 8 KB

    const int tj = lane & 15;
    const int ti = lane >> 4;

    const int e0   = W;
    const int c1_0 = edge_index[e0];
    const int c2_0 = edge_index[NE + e0];
    const int e1   = W + NE / 2;
    const int c1_1 = edge_index[e1];
    const int c2_1 = edge_index[NE + e1];

    // ---- issue ALL edge-0 staging loads + edge-1 x1 prefetch up-front ----
    const float4 A0  = load_pt<USE_WS>(data, clusts, ws, c1_0, lane);
    const float4 A1  = load_pt<USE_WS>(data, clusts, ws, c1_0, lane + 64);
    float4 Bv[8];
    #pragma unroll
    for (int m = 0; m < 8; ++m)
        Bv[m] = load_pt<USE_WS>(data, clusts, ws, c2_0, tj + 16 * m);
    const float4 A0n = load_pt<USE_WS>(data, clusts, ws, c1_1, lane);
    const float4 A1n = load_pt<USE_WS>(data, clusts, ws, c1_1, lane + 64);

    // ---- stage + compute edge 0 ----
    const float4* x1p0 = &x1buf[w][0][0];
    x1buf[w][0][lane]      = A0;
    x1buf[w][0][lane + 64] = A1;

    float bx[8], by[8], bz[8];
    #pragma unroll
    for (int m = 0; m < 8; ++m) { bx[m] = Bv[m].x; by[m] = Bv[m].y; bz[m] = Bv[m].z; }

    const unsigned long long key0 = wave_min_key(x1p0, bx, by, bz, ti, tj);

    // ---- stage edge-1 a-tile (loads long in flight); issue edge-1 b loads
    //      so they fly under edge-0's reduce tail + epilogue ----
    const float4* x1p1 = &x1buf[w][1][0];
    x1buf[w][1][lane]      = A0n;
    x1buf[w][1][lane + 64] = A1n;

    float4 Bn[8];
    #pragma unroll
    for (int m = 0; m < 8; ++m)
        Bn[m] = load_pt<USE_WS>(data, clusts, ws, c2_1, tj + 16 * m);

    if (lane == 0)
        epilogue<USE_WS>(key0, x1p0, data, clusts, ws, c2_0, e0, out);

    // ---- compute edge 1 ----
    #pragma unroll
    for (int m = 0; m < 8; ++m) { bx[m] = Bn[m].x; by[m] = Bn[m].y; bz[m] = Bn[m].z; }

    const unsigned long long key1 = wave_min_key(x1p1, bx, by, bz, ti, tj);

    if (lane == 0)
        epilogue<USE_WS>(key1, x1p1, data, clusts, ws, c2_1, e1, out);
}

extern "C" void kernel_launch(void* const* d_in, const int* in_sizes, int n_in,
                              void* d_out, int out_size, void* d_ws, size_t ws_size,
                              hipStream_t stream) {
    const float* data       = (const float*)d_in[0];
    const int*   clusts     = (const int*)d_in[1];
    const int*   edge_index = (const int*)d_in[2];
    float*       out        = (float*)d_out;
    float4*      ws         = (float4*)d_ws;

    const size_t need = (size_t)NC * P * sizeof(float4);  // 2 MB
    if (ws_size >= need) {
        gather_kernel<<<(NC * P) / 256, 256, 0, stream>>>(data, clusts, ws);
        clust_geo_edge_kernel<true><<<NE / 4, 128, 0, stream>>>(data, clusts, edge_index, ws, out);
    } else {
        clust_geo_edge_kernel<false><<<NE / 4, 128, 0, stream>>>(data, clusts, edge_index, ws, out);
    }
}

// Round 9
// 92.669 us; speedup vs baseline: 1.0356x; 1.0356x over previous
//
#include <hip/hip_runtime.h>
#include <cstdint>

#define NV 200000
#define NCOLS 5
#define P 128
#define NE 8192
#define NC 1024

// Kernel 1: gather all clusters' coords once into dense float4 array.
// ws[c*P + p] = (data[v,1], data[v,2], data[v,3], 0) where v = clusts[c,p].
__global__ __launch_bounds__(256) void gather_kernel(
    const float* __restrict__ data,
    const int*   __restrict__ clusts,
    float4*      __restrict__ ws)
{
    const int idx = blockIdx.x * 256 + threadIdx.x;   // 0 .. NC*P-1
    const int v = clusts[idx];
    ws[idx] = make_float4(data[v * NCOLS + 1], data[v * NCOLS + 2],
                          data[v * NCOLS + 3], 0.f);
}

// Edge kernel: ONE WAVE PER EDGE (128-thread block = 2 waves = 2 edges).
//
// Final form (harness-proven 93.2 us total). Session ladder:
//   R3 serial chain, 32 VGPR, 8 waves/SIMD:         42.0 us edge (latency: 256-link cmp chain)
//   R4 8 chains, full unroll, 216 VGPR, 2 waves:    73.0 us edge (occupancy collapse)
//   R5 8 chains, rolled groups of 8, ~4-5 waves:   ~38.6 us edge  << this kernel
//   R6 groups of 4 (7-8 waves):                     neutral-minus
//   R7 packed dual-f32:                             neutral
//   R8 2 edges/wave software pipeline:              regression (TLP already covers)
// Edge duty ~53% is invariant to occupancy, ILP, op packing, and
// cross-edge pipelining => structural at HIP level given the exact
// rounding + argmin tie-break constraints. Total is dominated by the
// harness poison fill (42 us @ 80% HBM peak) + gather + launch gaps.
//
// Tie-break exactness (HW-proven): within chain m, j = tj+16m fixed,
// k ascends (kk outer asc, u inner asc) => flat ascends; strict < keeps
// first (smallest-flat) min. Cross-chain (m asc) and cross-lane combines
// use packed (d2_bits<<32 | flat) u64 keys => lexicographic
// (min d2, then min flat), bit-identical to jnp.argmin.
//
// No __syncthreads: each wave writes and reads only its own LDS half.
template <bool USE_WS>
__global__ __launch_bounds__(128) void clust_geo_edge_kernel(
    const float*  __restrict__ data,
    const int*    __restrict__ clusts,
    const int*    __restrict__ edge_index,
    const float4* __restrict__ ws,
    float*        __restrict__ out)
{
    const int w    = threadIdx.x >> 6;     // wave id within block: 0/1
    const int lane = threadIdx.x & 63;
    const int e    = blockIdx.x * 2 + w;   // one edge per wave

    __shared__ float4 x1s[2][P];
    __shared__ float4 x2s[2][P];

    const int c1 = edge_index[e];
    const int c2 = edge_index[NE + e];

    // Stage both clusters (4 float4 loads/lane, coalesced on the ws path).
    if (USE_WS) {
        x1s[w][lane]      = ws[c1 * P + lane];
        x1s[w][lane + 64] = ws[c1 * P + lane + 64];
        x2s[w][lane]      = ws[c2 * P + lane];
        x2s[w][lane + 64] = ws[c2 * P + lane + 64];
    } else {
        int v = clusts[c1 * P + lane];
        x1s[w][lane]      = make_float4(data[v * NCOLS + 1], data[v * NCOLS + 2],
                                        data[v * NCOLS + 3], 0.f);
        v = clusts[c1 * P + lane + 64];
        x1s[w][lane + 64] = make_float4(data[v * NCOLS + 1], data[v * NCOLS + 2],
                                        data[v * NCOLS + 3], 0.f);
        v = clusts[c2 * P + lane];
        x2s[w][lane]      = make_float4(data[v * NCOLS + 1], data[v * NCOLS + 2],
                                        data[v * NCOLS + 3], 0.f);
        v = clusts[c2 * P + lane + 64];
        x2s[w][lane + 64] = make_float4(data[v * NCOLS + 1], data[v * NCOLS + 2],
                                        data[v * NCOLS + 3], 0.f);
    }
    // (no barrier needed — per-wave-private LDS halves)

    // 4x16 lane grid: i = ti + 4*k (k=0..31), j = tj + 16*m (m=0..7).
    const int tj = lane & 15;
    const int ti = lane >> 4;

    // b tile resident as scalars (24 VGPR, no dead .w lane).
    float bx[8], by[8], bz[8];
    #pragma unroll
    for (int m = 0; m < 8; ++m) {
        const float4 v = x2s[w][tj + 16 * m];
        bx[m] = v.x; by[m] = v.y; bz[m] = v.z;
    }

    // Eight independent (value, k-index) min-chains.
    float bd[8];
    int   bk[8];
    #pragma unroll
    for (int m = 0; m < 8; ++m) { bd[m] = __builtin_inff(); bk[m] = 0; }

    // Exact replication of reference fp32 arithmetic: (dx*dx + dy*dy) + dz*dz,
    // no FMA contraction (argmin tie-breaking must match numpy).
    // Rolled groups of 8 a-points: bounds a-liveness (24 scalar VGPRs) so
    // ~4-5 waves/SIMD stay resident while 64 independent pair computations
    // per group feed the issue pipe.
    #pragma unroll 1
    for (int kk = 0; kk < 4; ++kk) {
        float ax[8], ay[8], az[8];
        #pragma unroll
        for (int u = 0; u < 8; ++u) {
            const float4 av = x1s[w][ti + 4 * (kk * 8 + u)];   // broadcast read
            ax[u] = av.x; ay[u] = av.y; az[u] = av.z;
        }
        #pragma unroll
        for (int u = 0; u < 8; ++u) {
            #pragma unroll
            for (int m = 0; m < 8; ++m) {
                const float dx = __fsub_rn(ax[u], bx[m]);
                const float dy = __fsub_rn(ay[u], by[m]);
                const float dz = __fsub_rn(az[u], bz[m]);
                const float d2 = __fadd_rn(__fadd_rn(__fmul_rn(dx, dx), __fmul_rn(dy, dy)),
                                           __fmul_rn(dz, dz));
                if (d2 < bd[m]) { bd[m] = d2; bk[m] = kk * 8 + u; }  // k ascending
            }
        }
    }

    // Combine the 8 chains exactly via packed (d2, flat) keys.
    const int base = ti * P + tj;
    unsigned long long key = 0xffffffffffffffffull;
    #pragma unroll
    for (int m = 0; m < 8; ++m) {
        const unsigned flat = (unsigned)(base + (m << 4) + (bk[m] << 9)); // +512*k
        const unsigned long long km =
            ((unsigned long long)__float_as_uint(bd[m]) << 32) | flat;
        if (km < key) key = km;
    }

    // Wave-level (64-lane) min reduce — no cross-wave stage needed.
    for (int off = 32; off > 0; off >>= 1) {
        unsigned long long other = __shfl_down(key, off, 64);
        if (other < key) key = other;
    }

    if (lane == 0) {
        const int flat = (int)(key & 0xffffffffull);
        const int i1 = flat >> 7;
        const int i2 = flat & (P - 1);

        const float v1x = x1s[w][i1].x, v1y = x1s[w][i1].y, v1z = x1s[w][i1].z;
        const float v2x = x2s[w][i2].x, v2y = x2s[w][i2].y, v2z = x2s[w][i2].z;

        const float dx = v1x - v2x, dy = v1y - v2y, dz = v1z - v2z;
        const float lend = sqrtf(dx * dx + dy * dy + dz * dz);

        float nx, ny, nz;
        if (lend > 0.f) { nx = dx / lend; ny = dy / lend; nz = dz / lend; }
        else            { nx = dx;        ny = dy;        nz = dz;        }

        const float B[9] = { nx*nx, nx*ny, nx*nz,
                             ny*nx, ny*ny, ny*nz,
                             nz*nx, nz*ny, nz*nz };

        float* o = out + (size_t)e * 38;
        // feats: v1, v2, dispn, lend, B
        o[0] = v1x; o[1] = v1y; o[2] = v1z;
        o[3] = v2x; o[4] = v2y; o[5] = v2z;
        o[6] = nx;  o[7] = ny;  o[8] = nz;  o[9] = lend;
        #pragma unroll
        for (int q = 0; q < 9; ++q) o[10 + q] = B[q];
        // feats_flip: v2, v1, -dispn, lend, B
        o[19] = v2x; o[20] = v2y; o[21] = v2z;
        o[22] = v1x; o[23] = v1y; o[24] = v1z;
        o[25] = -nx; o[26] = -ny; o[27] = -nz; o[28] = lend;
        #pragma unroll
        for (int q = 0; q < 9; ++q) o[29 + q] = B[q];
    }
}

extern "C" void kernel_launch(void* const* d_in, const int* in_sizes, int n_in,
                              void* d_out, int out_size, void* d_ws, size_t ws_size,
                              hipStream_t stream) {
    const float* data       = (const float*)d_in[0];
    const int*   clusts     = (const int*)d_in[1];
    const int*   edge_index = (const int*)d_in[2];
    float*       out        = (float*)d_out;
    float4*      ws         = (float4*)d_ws;

    const size_t need = (size_t)NC * P * sizeof(float4);  // 2 MB
    if (ws_size >= need) {
        gather_kernel<<<(NC * P) / 256, 256, 0, stream>>>(data, clusts, ws);
        clust_geo_edge_kernel<true><<<NE / 2, 128, 0, stream>>>(data, clusts, edge_index, ws, out);
    } else {
        clust_geo_edge_kernel<false><<<NE / 2, 128, 0, stream>>>(data, clusts, edge_index, ws, out);
    }
}